// Round 6
// baseline (220.209 us; speedup 1.0000x reference)
//
#include <hip/hip_runtime.h>

// StableContrastiveLoss on MI355X (gfx950).  B=4096, D=512, C=10, T=0.07.
// Round 6: R5's 64x64 upper-triangle structure (2080 blocks = 8 blk/CU, the
// proven-occupancy regime) with staging switched to global_load_lds 16B DMA
// + XOR chunk swizzle (R3-proven, 0 bank conflicts), removing 4 ds_write_b128
// and 4 vmcnt round-trips per wave per K-iter. Finalize fused via ticket.
// 2 dispatches.
// ws: F_bf16 [4096*512] | cls [4096] | pos_sum [4096] | all_sum [4096] | done

#define B_ROWS 4096
#define D_DIM  512
#define C_CLS  10
#define NT     64                     // 4096/64 tiles per dim
#define NTILES (NT * (NT + 1) / 2)    // 2080 upper-triangle tiles

typedef __bf16 bf16x8 __attribute__((ext_vector_type(8)));
typedef float  f32x4  __attribute__((ext_vector_type(4)));

// async global->LDS DMA, 16B/lane; LDS dest = wave-uniform base + lane*16
__device__ __forceinline__ void load_lds16(const __bf16* g, __bf16* l) {
  __builtin_amdgcn_global_load_lds(
      (const __attribute__((address_space(1))) unsigned int*)g,
      (__attribute__((address_space(3))) unsigned int*)l, 16, 0, 0);
}

// ---------------- Kernel 1: normalize rows + class extract + zero accum ----
__global__ __launch_bounds__(256) void prep_kernel(
    const float* __restrict__ feats, const float* __restrict__ labels,
    __bf16* __restrict__ F, int* __restrict__ cls,
    float* __restrict__ pos_sum, float* __restrict__ all_sum,
    int* __restrict__ done) {
  const int w = threadIdx.x >> 6, lane = threadIdx.x & 63;
  const int row = blockIdx.x * 4 + w;   // one wave per row
  const float* fr = feats + (size_t)row * D_DIM;
  float4 v0 = ((const float4*)fr)[2 * lane];
  float4 v1 = ((const float4*)fr)[2 * lane + 1];
  float ss = v0.x*v0.x + v0.y*v0.y + v0.z*v0.z + v0.w*v0.w
           + v1.x*v1.x + v1.y*v1.y + v1.z*v1.z + v1.w*v1.w;
  #pragma unroll
  for (int m = 1; m < 64; m <<= 1) ss += __shfl_xor(ss, m, 64);
  float inv = 1.0f / sqrtf(ss);

  bf16x8 o;
  o[0] = (__bf16)(v0.x * inv); o[1] = (__bf16)(v0.y * inv);
  o[2] = (__bf16)(v0.z * inv); o[3] = (__bf16)(v0.w * inv);
  o[4] = (__bf16)(v1.x * inv); o[5] = (__bf16)(v1.y * inv);
  o[6] = (__bf16)(v1.z * inv); o[7] = (__bf16)(v1.w * inv);
  *(bf16x8*)(F + (size_t)row * D_DIM + 8 * lane) = o;

  float lv = (lane < C_CLS) ? labels[(size_t)row * C_CLS + lane] : 0.f;
  unsigned long long m = __ballot(lv > 0.5f);
  if (lane == 0) {
    cls[row] = (int)(__ffsll((long long)m) - 1);
    pos_sum[row] = 0.f;
    all_sum[row] = 0.f;
  }
  if (blockIdx.x == 0 && threadIdx.x == 0) *done = 0;
}

// --- Kernel 2: symmetric 64x64-tile sim + exp + row/col sums + finalize ----
// LDS layout: unpadded 64x64 bf16 per operand (row = 8 chunks of 16B);
// LDS[row][c] holds global chunk (c ^ (row&7)) -> swizzled conflict-free
// b128 reads AND DMA-compatible (dest = uniform base + lane*16).
__global__ __launch_bounds__(256) void sim_kernel(
    const __bf16* __restrict__ F, const int* __restrict__ cls,
    float* __restrict__ pos_sum, float* __restrict__ all_sum,
    int* __restrict__ done, float* __restrict__ out) {
  __shared__ __align__(16) __bf16 Abuf[64 * 64];
  __shared__ __align__(16) __bf16 Bbuf[64 * 64];
  __shared__ int clsA[64], clsB[64];
  __shared__ int ticket_s;
  __shared__ float redv[8];

  // triangular tile decode (block-uniform scalar loop, <=64 iters)
  int rem = blockIdx.x, bi = 0, rowlen = NT;
  while (rem >= rowlen) { rem -= rowlen; ++bi; --rowlen; }
  const int bj = bi + rem;
  const int i0 = bi * 64, j0 = bj * 64;
  const bool offdiag = (bi != bj);

  const int t = threadIdx.x;       // 256 threads = 4 waves
  const int w = t >> 6;
  const int lane = t & 63;
  const int q = lane >> 4;         // quad (k-group / acc-row selector)
  const int cl = lane & 15;        // fragment row/col index

  if (t < 64)       clsA[t]      = cls[i0 + t];
  else if (t < 128) clsB[t - 64] = cls[j0 + t - 64];

  f32x4 acc[4];
  #pragma unroll
  for (int c = 0; c < 4; ++c) acc[c] = (f32x4){0.f, 0.f, 0.f, 0.f};

  // DMA roles: lane L -> subrow L/8 (0..7), LDS chunk L%8; global chunk
  // to fetch = (L%8) ^ (L/8) so that LDS[row][c] = global chunk c^(row&7).
  const int srow = lane >> 3;
  const int sg   = (lane & 7) ^ srow;

  for (int k0 = 0; k0 < D_DIM; k0 += 64) {
    __syncthreads();  // previous iteration's readers done (also covers clsA/B)
    #pragma unroll
    for (int r = 0; r < 2; ++r) {
      const int rowbase = w * 16 + r * 8;   // wave-uniform, multiple of 8
      load_lds16(F + (size_t)(i0 + rowbase + srow) * D_DIM + k0 + sg * 8,
                 &Abuf[rowbase * 64]);
      load_lds16(F + (size_t)(j0 + rowbase + srow) * D_DIM + k0 + sg * 8,
                 &Bbuf[rowbase * 64]);
    }
    __syncthreads();  // barrier drain (vmcnt(0)) completes the DMA

    #pragma unroll
    for (int kk = 0; kk < 64; kk += 32) {
      const int g = (kk >> 3) + q;          // logical 16B chunk index
      const int cc = g ^ (cl & 7);          // swizzled LDS chunk
      bf16x8 af = *(const bf16x8*)&Abuf[(16 * w + cl) * 64 + cc * 8];
      #pragma unroll
      for (int c = 0; c < 4; ++c) {
        bf16x8 bfr = *(const bf16x8*)&Bbuf[(16 * c + cl) * 64 + cc * 8];
        acc[c] = __builtin_amdgcn_mfma_f32_16x16x32_bf16(af, bfr, acc[c], 0, 0, 0);
      }
    }
  }

  // Epilogue. D layout (m89/m91): col = lane&15, row = (lane>>4)*4 + reg.
  const float invT = 1.0f / 0.07f;
  float sum_all[4] = {0.f, 0.f, 0.f, 0.f};
  float sum_pos[4] = {0.f, 0.f, 0.f, 0.f};
  float cs_all[4]  = {0.f, 0.f, 0.f, 0.f};
  float cs_pos[4]  = {0.f, 0.f, 0.f, 0.f};

  #pragma unroll
  for (int c = 0; c < 4; ++c) {
    const int jloc = 16*c + cl;
    const int gj = j0 + jloc;
    const int cj = clsB[jloc];
    #pragma unroll
    for (int r = 0; r < 4; ++r) {
      const int iloc = 16*w + q*4 + r;
      const int gi = i0 + iloc;
      float s = acc[c][r] * invT;
      s = fminf(fmaxf(s, -20.f), 20.f);
      const bool diag = (gi == gj);
      float e = diag ? 0.f : __expf(s);
      sum_all[r] += e;
      cs_all[c] += e;
      if (!diag && cj == clsA[iloc]) { sum_pos[r] += e; cs_pos[c] += e; }
    }
  }

  // row sums: reduce across 16 lanes of each quad -> 2 atomics per row
  #pragma unroll
  for (int r = 0; r < 4; ++r) {
    float sa = sum_all[r], sp = sum_pos[r];
    #pragma unroll
    for (int m = 1; m < 16; m <<= 1) {
      sa += __shfl_xor(sa, m, 64);
      sp += __shfl_xor(sp, m, 64);
    }
    if (cl == 0) {
      const int gi = i0 + 16*w + q*4 + r;
      atomicAdd(&all_sum[gi], sa);
      atomicAdd(&pos_sum[gi], sp);
    }
  }

  // col sums (symmetry mirror, off-diag only): reduce across quads
  if (offdiag) {
    #pragma unroll
    for (int c = 0; c < 4; ++c) {
      float sa = cs_all[c], sp = cs_pos[c];
      sa += __shfl_xor(sa, 16, 64); sa += __shfl_xor(sa, 32, 64);
      sp += __shfl_xor(sp, 16, 64); sp += __shfl_xor(sp, 32, 64);
      if (q == 0) {
        const int gj = j0 + 16*c + cl;
        atomicAdd(&all_sum[gj], sa);
        atomicAdd(&pos_sum[gj], sp);
      }
    }
  }

  // ---- fused finalize: last block to finish reduces the loss ----
  __threadfence();           // release our atomics
  __syncthreads();
  if (t == 0) ticket_s = atomicAdd(done, 1);
  __syncthreads();
  if (ticket_s == NTILES - 1) {   // block-uniform
    __threadfence();         // acquire all other blocks' sums
    float total = 0.f, cnt = 0.f;
    for (int i = t; i < B_ROWS; i += 256) {
      float ps = pos_sum[i], as = all_sum[i];
      if (ps > 0.f) {        // valid iff >=1 positive (exp > 0 always)
        total += -__logf(ps / (as + 1e-8f) + 1e-8f);
        cnt += 1.f;
      }
    }
    #pragma unroll
    for (int m = 1; m < 64; m <<= 1) {
      total += __shfl_xor(total, m, 64);
      cnt   += __shfl_xor(cnt, m, 64);
    }
    if ((t & 63) == 0) { redv[t >> 6] = total; redv[4 + (t >> 6)] = cnt; }
    __syncthreads();
    if (t == 0) {
      float T = 0.f, Cn = 0.f;
      #pragma unroll
      for (int i = 0; i < 4; ++i) { T += redv[i]; Cn += redv[4 + i]; }
      out[0] = (Cn > 0.f) ? (T / Cn) : 0.f;
    }
  }
}

extern "C" void kernel_launch(void* const* d_in, const int* in_sizes, int n_in,
                              void* d_out, int out_size, void* d_ws, size_t ws_size,
                              hipStream_t stream) {
  const float* features = (const float*)d_in[0];
  const float* labels   = (const float*)d_in[1];
  float* out = (float*)d_out;

  __bf16* F       = (__bf16*)d_ws;
  int*    cls     = (int*)((char*)d_ws + (size_t)B_ROWS * D_DIM * 2);
  float*  pos_sum = (float*)((char*)cls + B_ROWS * sizeof(int));
  float*  all_sum = pos_sum + B_ROWS;
  int*    done    = (int*)(all_sum + B_ROWS);

  prep_kernel<<<B_ROWS / 4, 256, 0, stream>>>(features, labels, F, cls,
                                              pos_sum, all_sum, done);
  sim_kernel<<<NTILES, 256, 0, stream>>>(F, cls, pos_sum, all_sum, done, out);
}

// Round 7
// 98.000 us; speedup vs baseline: 2.2470x; 2.2470x over previous
//
#include <hip/hip_runtime.h>

// StableContrastiveLoss on MI355X (gfx950).  B=4096, D=512, C=10, T=0.07.
// Round 7: R6 minus the fused finalize/__threadfence. R1..R6 post-mortem:
// every kernel containing a per-block __threadfence ran at 50-100 TF eff.
// regardless of memory structure (R4 no-LDS, R3/R6 DMA); every fence-free
// kernel ran ~350 TF. Fence cost ~75-150ns/block serialized (L2 writeback),
// scales with block count -> NEVER fence per-block. This round isolates
// DMA staging vs R5's VALU staging with no fence: 2080 upper-tri 64x64
// tiles, global_load_lds 16B + XOR swizzle, 3 dispatches.
// ws: F_bf16 [4096*512] | cls [4096] | pos_sum [4096] | all_sum [4096]

#define B_ROWS 4096
#define D_DIM  512
#define C_CLS  10
#define NT     64                     // 4096/64 tiles per dim
#define NTILES (NT * (NT + 1) / 2)    // 2080 upper-triangle tiles

typedef __bf16 bf16x8 __attribute__((ext_vector_type(8)));
typedef float  f32x4  __attribute__((ext_vector_type(4)));

// async global->LDS DMA, 16B/lane; LDS dest = wave-uniform base + lane*16
__device__ __forceinline__ void load_lds16(const __bf16* g, __bf16* l) {
  __builtin_amdgcn_global_load_lds(
      (const __attribute__((address_space(1))) unsigned int*)g,
      (__attribute__((address_space(3))) unsigned int*)l, 16, 0, 0);
}

// ---------------- Kernel 1: normalize rows + class extract + zero accum ----
__global__ __launch_bounds__(256) void prep_kernel(
    const float* __restrict__ feats, const float* __restrict__ labels,
    __bf16* __restrict__ F, int* __restrict__ cls,
    float* __restrict__ pos_sum, float* __restrict__ all_sum) {
  const int w = threadIdx.x >> 6, lane = threadIdx.x & 63;
  const int row = blockIdx.x * 4 + w;   // one wave per row
  const float* fr = feats + (size_t)row * D_DIM;
  float4 v0 = ((const float4*)fr)[2 * lane];
  float4 v1 = ((const float4*)fr)[2 * lane + 1];
  float ss = v0.x*v0.x + v0.y*v0.y + v0.z*v0.z + v0.w*v0.w
           + v1.x*v1.x + v1.y*v1.y + v1.z*v1.z + v1.w*v1.w;
  #pragma unroll
  for (int m = 1; m < 64; m <<= 1) ss += __shfl_xor(ss, m, 64);
  float inv = 1.0f / sqrtf(ss);

  bf16x8 o;
  o[0] = (__bf16)(v0.x * inv); o[1] = (__bf16)(v0.y * inv);
  o[2] = (__bf16)(v0.z * inv); o[3] = (__bf16)(v0.w * inv);
  o[4] = (__bf16)(v1.x * inv); o[5] = (__bf16)(v1.y * inv);
  o[6] = (__bf16)(v1.z * inv); o[7] = (__bf16)(v1.w * inv);
  *(bf16x8*)(F + (size_t)row * D_DIM + 8 * lane) = o;

  float lv = (lane < C_CLS) ? labels[(size_t)row * C_CLS + lane] : 0.f;
  unsigned long long m = __ballot(lv > 0.5f);
  if (lane == 0) {
    cls[row] = (int)(__ffsll((long long)m) - 1);
    pos_sum[row] = 0.f;
    all_sum[row] = 0.f;
  }
}

// --------- Kernel 2: symmetric 64x64-tile sim + exp + row/col sums ---------
// LDS layout: unpadded 64x64 bf16 per operand (row = 8 chunks of 16B);
// LDS[row][c] holds global chunk (c ^ (row&7)) -> swizzled conflict-free
// b128 reads AND DMA-compatible (dest = uniform base + lane*16).
__global__ __launch_bounds__(256) void sim_kernel(
    const __bf16* __restrict__ F, const int* __restrict__ cls,
    float* __restrict__ pos_sum, float* __restrict__ all_sum) {
  __shared__ __align__(16) __bf16 Abuf[64 * 64];
  __shared__ __align__(16) __bf16 Bbuf[64 * 64];
  __shared__ int clsA[64], clsB[64];

  // triangular tile decode (block-uniform scalar loop, <=64 iters)
  int rem = blockIdx.x, bi = 0, rowlen = NT;
  while (rem >= rowlen) { rem -= rowlen; ++bi; --rowlen; }
  const int bj = bi + rem;
  const int i0 = bi * 64, j0 = bj * 64;
  const bool offdiag = (bi != bj);

  const int t = threadIdx.x;       // 256 threads = 4 waves
  const int w = t >> 6;
  const int lane = t & 63;
  const int q = lane >> 4;         // quad (k-group / acc-row selector)
  const int cl = lane & 15;        // fragment row/col index

  if (t < 64)       clsA[t]      = cls[i0 + t];
  else if (t < 128) clsB[t - 64] = cls[j0 + t - 64];

  f32x4 acc[4];
  #pragma unroll
  for (int c = 0; c < 4; ++c) acc[c] = (f32x4){0.f, 0.f, 0.f, 0.f};

  // DMA roles: lane L -> subrow L/8 (0..7), LDS chunk L%8; global chunk
  // to fetch = (L%8) ^ (L/8) so that LDS[row][c] = global chunk c^(row&7).
  const int srow = lane >> 3;
  const int sg   = (lane & 7) ^ srow;

  for (int k0 = 0; k0 < D_DIM; k0 += 64) {
    __syncthreads();  // previous iteration's readers done (also covers clsA/B)
    #pragma unroll
    for (int r = 0; r < 2; ++r) {
      const int rowbase = w * 16 + r * 8;   // wave-uniform, multiple of 8
      load_lds16(F + (size_t)(i0 + rowbase + srow) * D_DIM + k0 + sg * 8,
                 &Abuf[rowbase * 64]);
      load_lds16(F + (size_t)(j0 + rowbase + srow) * D_DIM + k0 + sg * 8,
                 &Bbuf[rowbase * 64]);
    }
    __syncthreads();  // barrier drain (vmcnt(0)) completes the DMA

    #pragma unroll
    for (int kk = 0; kk < 64; kk += 32) {
      const int g = (kk >> 3) + q;          // logical 16B chunk index
      const int cc = g ^ (cl & 7);          // swizzled LDS chunk
      bf16x8 af = *(const bf16x8*)&Abuf[(16 * w + cl) * 64 + cc * 8];
      #pragma unroll
      for (int c = 0; c < 4; ++c) {
        bf16x8 bfr = *(const bf16x8*)&Bbuf[(16 * c + cl) * 64 + cc * 8];
        acc[c] = __builtin_amdgcn_mfma_f32_16x16x32_bf16(af, bfr, acc[c], 0, 0, 0);
      }
    }
  }

  // Epilogue. D layout (m89/m91): col = lane&15, row = (lane>>4)*4 + reg.
  const float invT = 1.0f / 0.07f;
  float sum_all[4] = {0.f, 0.f, 0.f, 0.f};
  float sum_pos[4] = {0.f, 0.f, 0.f, 0.f};
  float cs_all[4]  = {0.f, 0.f, 0.f, 0.f};
  float cs_pos[4]  = {0.f, 0.f, 0.f, 0.f};

  #pragma unroll
  for (int c = 0; c < 4; ++c) {
    const int jloc = 16*c + cl;
    const int gj = j0 + jloc;
    const int cj = clsB[jloc];
    #pragma unroll
    for (int r = 0; r < 4; ++r) {
      const int iloc = 16*w + q*4 + r;
      const int gi = i0 + iloc;
      float s = acc[c][r] * invT;
      s = fminf(fmaxf(s, -20.f), 20.f);
      const bool diag = (gi == gj);
      float e = diag ? 0.f : __expf(s);
      sum_all[r] += e;
      cs_all[c] += e;
      if (!diag && cj == clsA[iloc]) { sum_pos[r] += e; cs_pos[c] += e; }
    }
  }

  // row sums: reduce across 16 lanes of each quad -> 2 atomics per row
  #pragma unroll
  for (int r = 0; r < 4; ++r) {
    float sa = sum_all[r], sp = sum_pos[r];
    #pragma unroll
    for (int m = 1; m < 16; m <<= 1) {
      sa += __shfl_xor(sa, m, 64);
      sp += __shfl_xor(sp, m, 64);
    }
    if (cl == 0) {
      const int gi = i0 + 16*w + q*4 + r;
      atomicAdd(&all_sum[gi], sa);
      atomicAdd(&pos_sum[gi], sp);
    }
  }

  // col sums (symmetry mirror, off-diag only): reduce across quads
  if (offdiag) {
    #pragma unroll
    for (int c = 0; c < 4; ++c) {
      float sa = cs_all[c], sp = cs_pos[c];
      sa += __shfl_xor(sa, 16, 64); sa += __shfl_xor(sa, 32, 64);
      sp += __shfl_xor(sp, 16, 64); sp += __shfl_xor(sp, 32, 64);
      if (q == 0) {
        const int gj = j0 + 16*c + cl;
        atomicAdd(&all_sum[gj], sa);
        atomicAdd(&pos_sum[gj], sp);
      }
    }
  }
}

// ---------------- Kernel 3: final loss reduction ----------------
__global__ __launch_bounds__(256) void finalize_kernel(
    const float* __restrict__ pos_sum, const float* __restrict__ all_sum,
    float* __restrict__ out) {
  __shared__ float redT[4], redC[4];
  const int t = threadIdx.x;
  float total = 0.f, cnt = 0.f;
  for (int i = t; i < B_ROWS; i += 256) {
    float ps = pos_sum[i], as = all_sum[i];
    if (ps > 0.f) {   // row valid iff >=1 positive (exp > 0 always)
      total += -logf(ps / (as + 1e-8f) + 1e-8f);
      cnt += 1.f;
    }
  }
  #pragma unroll
  for (int m = 1; m < 64; m <<= 1) {
    total += __shfl_xor(total, m, 64);
    cnt   += __shfl_xor(cnt, m, 64);
  }
  if ((t & 63) == 0) { redT[t >> 6] = total; redC[t >> 6] = cnt; }
  __syncthreads();
  if (t == 0) {
    float T = 0.f, Cn = 0.f;
    #pragma unroll
    for (int i = 0; i < 4; ++i) { T += redT[i]; Cn += redC[i]; }
    out[0] = (Cn > 0.f) ? (T / Cn) : 0.f;
  }
}

extern "C" void kernel_launch(void* const* d_in, const int* in_sizes, int n_in,
                              void* d_out, int out_size, void* d_ws, size_t ws_size,
                              hipStream_t stream) {
  const float* features = (const float*)d_in[0];
  const float* labels   = (const float*)d_in[1];
  float* out = (float*)d_out;

  __bf16* F       = (__bf16*)d_ws;
  int*    cls     = (int*)((char*)d_ws + (size_t)B_ROWS * D_DIM * 2);
  float*  pos_sum = (float*)((char*)cls + B_ROWS * sizeof(int));
  float*  all_sum = pos_sum + B_ROWS;

  prep_kernel<<<B_ROWS / 4, 256, 0, stream>>>(features, labels, F, cls,
                                              pos_sum, all_sum);
  sim_kernel<<<NTILES, 256, 0, stream>>>(F, cls, pos_sum, all_sum);
  finalize_kernel<<<1, 256, 0, stream>>>(pos_sum, all_sum, out);
}

// Round 8
// 93.702 us; speedup vs baseline: 2.3501x; 1.0459x over previous
//
#include <hip/hip_runtime.h>

// StableContrastiveLoss on MI355X (gfx950).  B=4096, D=512, C=10, T=0.07.
// Round 8: ATOMIC-FREE sim. R1/R5/R7 post-mortem: fence-free sim kernels all
// land ~40-45us while FLOPs/exp/L2 halved and staging changed -- the only
// invariant is ~524k device atomicAdd ops to a 32KB hot region. This round
// replaces them with exactly-once contiguous stores to a partial tensor
// P[strip][slot][row] (slot t of strip s: tile(s,t) row-sums if t>=s, else
// tile(t,s) col-sums -- disjoint+complete, safe vs 0xAA poison), reduced by
// a 64-block finalize. NEVER per-block __threadfence (R6: 75-150ns/block).
// ws: F_bf16[4096*512] | cls[4096] | P_all[64*64*64] | P_pos[...] | totals[2]

#define B_ROWS 4096
#define D_DIM  512
#define C_CLS  10
#define NT     64                     // 4096/64 tiles per dim
#define NTILES (NT * (NT + 1) / 2)    // 2080 upper-triangle tiles

typedef __bf16 bf16x8 __attribute__((ext_vector_type(8)));
typedef float  f32x4  __attribute__((ext_vector_type(4)));

// async global->LDS DMA, 16B/lane; LDS dest = wave-uniform base + lane*16
__device__ __forceinline__ void load_lds16(const __bf16* g, __bf16* l) {
  __builtin_amdgcn_global_load_lds(
      (const __attribute__((address_space(1))) unsigned int*)g,
      (__attribute__((address_space(3))) unsigned int*)l, 16, 0, 0);
}

// ---------------- Kernel 1: normalize rows + class extract ----------------
__global__ __launch_bounds__(256) void prep_kernel(
    const float* __restrict__ feats, const float* __restrict__ labels,
    __bf16* __restrict__ F, int* __restrict__ cls,
    float* __restrict__ totals) {
  const int w = threadIdx.x >> 6, lane = threadIdx.x & 63;
  const int row = blockIdx.x * 4 + w;   // one wave per row
  const float* fr = feats + (size_t)row * D_DIM;
  float4 v0 = ((const float4*)fr)[2 * lane];
  float4 v1 = ((const float4*)fr)[2 * lane + 1];
  float ss = v0.x*v0.x + v0.y*v0.y + v0.z*v0.z + v0.w*v0.w
           + v1.x*v1.x + v1.y*v1.y + v1.z*v1.z + v1.w*v1.w;
  #pragma unroll
  for (int m = 1; m < 64; m <<= 1) ss += __shfl_xor(ss, m, 64);
  float inv = 1.0f / sqrtf(ss);

  bf16x8 o;
  o[0] = (__bf16)(v0.x * inv); o[1] = (__bf16)(v0.y * inv);
  o[2] = (__bf16)(v0.z * inv); o[3] = (__bf16)(v0.w * inv);
  o[4] = (__bf16)(v1.x * inv); o[5] = (__bf16)(v1.y * inv);
  o[6] = (__bf16)(v1.z * inv); o[7] = (__bf16)(v1.w * inv);
  *(bf16x8*)(F + (size_t)row * D_DIM + 8 * lane) = o;

  float lv = (lane < C_CLS) ? labels[(size_t)row * C_CLS + lane] : 0.f;
  unsigned long long m = __ballot(lv > 0.5f);
  if (lane == 0) cls[row] = (int)(__ffsll((long long)m) - 1);
  if (blockIdx.x == 0 && threadIdx.x == 0) { totals[0] = 0.f; totals[1] = 0.f; }
}

// --------- Kernel 2: symmetric 64x64-tile sim, NO global atomics -----------
// LDS: unpadded 64x64 bf16 per operand; LDS[row][c] = global chunk c^(row&7)
// (DMA-compatible + conflict-free b128 reads). Partials stored exactly once:
// tile(bi,bj) -> P[bi][bj][r] (row sums), P[bj][bi][r] (col sums, offdiag).
__global__ __launch_bounds__(256) void sim_kernel(
    const __bf16* __restrict__ F, const int* __restrict__ cls,
    float* __restrict__ P_all, float* __restrict__ P_pos) {
  __shared__ __align__(16) __bf16 Abuf[64 * 64];
  __shared__ __align__(16) __bf16 Bbuf[64 * 64];
  __shared__ int clsA[64], clsB[64];
  __shared__ float g_row_all[64], g_row_pos[64];
  __shared__ float g_col_all[64], g_col_pos[64];

  // triangular tile decode (block-uniform scalar loop, <=64 iters)
  int rem = blockIdx.x, bi = 0, rowlen = NT;
  while (rem >= rowlen) { rem -= rowlen; ++bi; --rowlen; }
  const int bj = bi + rem;
  const int i0 = bi * 64, j0 = bj * 64;
  const bool offdiag = (bi != bj);

  const int t = threadIdx.x;       // 256 threads = 4 waves
  const int w = t >> 6;
  const int lane = t & 63;
  const int q = lane >> 4;         // quad
  const int cl = lane & 15;

  if (t < 64)       clsA[t]      = cls[i0 + t];
  else if (t < 128) clsB[t - 64] = cls[j0 + t - 64];
  if (t < 64) { g_col_all[t] = 0.f; g_col_pos[t] = 0.f; }

  f32x4 acc[4];
  #pragma unroll
  for (int c = 0; c < 4; ++c) acc[c] = (f32x4){0.f, 0.f, 0.f, 0.f};

  // DMA roles: lane L -> subrow L/8, LDS chunk L%8, global chunk (L%8)^(L/8)
  const int srow = lane >> 3;
  const int sg   = (lane & 7) ^ srow;

  for (int k0 = 0; k0 < D_DIM; k0 += 64) {
    __syncthreads();  // previous readers done (also covers cls/g_col init)
    #pragma unroll
    for (int r = 0; r < 2; ++r) {
      const int rowbase = w * 16 + r * 8;   // wave-uniform
      load_lds16(F + (size_t)(i0 + rowbase + srow) * D_DIM + k0 + sg * 8,
                 &Abuf[rowbase * 64]);
      load_lds16(F + (size_t)(j0 + rowbase + srow) * D_DIM + k0 + sg * 8,
                 &Bbuf[rowbase * 64]);
    }
    __syncthreads();  // barrier drain completes the DMA

    #pragma unroll
    for (int kk = 0; kk < 64; kk += 32) {
      const int g = (kk >> 3) + q;
      const int cc = g ^ (cl & 7);
      bf16x8 af = *(const bf16x8*)&Abuf[(16 * w + cl) * 64 + cc * 8];
      #pragma unroll
      for (int c = 0; c < 4; ++c) {
        bf16x8 bfr = *(const bf16x8*)&Bbuf[(16 * c + cl) * 64 + cc * 8];
        acc[c] = __builtin_amdgcn_mfma_f32_16x16x32_bf16(af, bfr, acc[c], 0, 0, 0);
      }
    }
  }

  // Epilogue. D layout (m89/m91): col = lane&15, row = (lane>>4)*4 + reg.
  const float invT = 1.0f / 0.07f;
  float sum_all[4] = {0.f, 0.f, 0.f, 0.f};
  float sum_pos[4] = {0.f, 0.f, 0.f, 0.f};
  float cs_all[4]  = {0.f, 0.f, 0.f, 0.f};
  float cs_pos[4]  = {0.f, 0.f, 0.f, 0.f};

  #pragma unroll
  for (int c = 0; c < 4; ++c) {
    const int jloc = 16*c + cl;
    const int gj = j0 + jloc;
    const int cj = clsB[jloc];
    #pragma unroll
    for (int r = 0; r < 4; ++r) {
      const int iloc = 16*w + q*4 + r;
      const int gi = i0 + iloc;
      float s = acc[c][r] * invT;
      s = fminf(fmaxf(s, -20.f), 20.f);
      const bool diag = (gi == gj);
      float e = diag ? 0.f : __expf(s);
      sum_all[r] += e;
      cs_all[c] += e;
      if (!diag && cj == clsA[iloc]) { sum_pos[r] += e; cs_pos[c] += e; }
    }
  }

  // row sums -> LDS (each row written exactly once: lanes cl==0)
  #pragma unroll
  for (int r = 0; r < 4; ++r) {
    float sa = sum_all[r], sp = sum_pos[r];
    #pragma unroll
    for (int m = 1; m < 16; m <<= 1) {
      sa += __shfl_xor(sa, m, 64);
      sp += __shfl_xor(sp, m, 64);
    }
    if (cl == 0) {
      const int rloc = 16*w + q*4 + r;
      g_row_all[rloc] = sa;
      g_row_pos[rloc] = sp;
    }
  }

  // col sums: per-wave partial (covers the wave's 16 rows) -> LDS atomicAdd
  // (LDS-scope, cheap) to combine the 4 waves
  if (offdiag) {
    #pragma unroll
    for (int c = 0; c < 4; ++c) {
      float sa = cs_all[c], sp = cs_pos[c];
      sa += __shfl_xor(sa, 16, 64); sa += __shfl_xor(sa, 32, 64);
      sp += __shfl_xor(sp, 16, 64); sp += __shfl_xor(sp, 32, 64);
      if (q == 0) {
        atomicAdd(&g_col_all[16*c + cl], sa);
        atomicAdd(&g_col_pos[16*c + cl], sp);
      }
    }
  }
  __syncthreads();

  // store phase: coalesced 256B stores, exactly-once slot coverage
  const size_t base_row = ((size_t)bi * 64 + bj) * 64;
  if (w == 0) {
    P_all[base_row + lane] = g_row_all[lane];
    P_pos[base_row + lane] = g_row_pos[lane];
  } else if (w == 1 && offdiag) {
    const size_t base_col = ((size_t)bj * 64 + bi) * 64;
    P_all[base_col + lane] = g_col_all[lane];
    P_pos[base_col + lane] = g_col_pos[lane];
  }
}

// ---- Kernel 3: per-strip reduction (64 blocks), tiny atomics to totals ----
__global__ __launch_bounds__(256) void finalize_kernel(
    const float* __restrict__ P_all, const float* __restrict__ P_pos,
    float* __restrict__ totals) {
  __shared__ float Sall[4096], Spos[4096];   // 32 KB
  const int s = blockIdx.x;
  const int t = threadIdx.x;
  for (int i = t; i < 4096; i += 256) {
    Sall[i] = P_all[(size_t)s * 4096 + i];   // coalesced
    Spos[i] = P_pos[(size_t)s * 4096 + i];
  }
  __syncthreads();
  if (t < 64) {   // wave 0: row r = t of this strip
    float a = 0.f, p = 0.f;
    #pragma unroll 8
    for (int k = 0; k < 64; ++k) {   // column sum: 2-way bank alias (free)
      a += Sall[k * 64 + t];
      p += Spos[k * 64 + t];
    }
    float loss = 0.f, cnt = 0.f;
    if (p > 0.f) {                   // valid iff >=1 positive
      loss = -logf(p / (a + 1e-8f) + 1e-8f);
      cnt = 1.f;
    }
    #pragma unroll
    for (int m = 1; m < 64; m <<= 1) {
      loss += __shfl_xor(loss, m, 64);
      cnt  += __shfl_xor(cnt, m, 64);
    }
    if (t == 0) {                    // 128 atomics total across the grid
      atomicAdd(&totals[0], loss);
      atomicAdd(&totals[1], cnt);
    }
  }
}

// ---------------- Kernel 4: scalar division ----------------
__global__ void div_kernel(const float* __restrict__ totals,
                           float* __restrict__ out) {
  out[0] = (totals[1] > 0.f) ? (totals[0] / totals[1]) : 0.f;
}

extern "C" void kernel_launch(void* const* d_in, const int* in_sizes, int n_in,
                              void* d_out, int out_size, void* d_ws, size_t ws_size,
                              hipStream_t stream) {
  const float* features = (const float*)d_in[0];
  const float* labels   = (const float*)d_in[1];
  float* out = (float*)d_out;

  __bf16* F      = (__bf16*)d_ws;
  int*    cls    = (int*)((char*)d_ws + (size_t)B_ROWS * D_DIM * 2);
  float*  P_all  = (float*)((char*)cls + B_ROWS * sizeof(int));
  float*  P_pos  = P_all + (size_t)NT * NT * 64;
  float*  totals = P_pos + (size_t)NT * NT * 64;

  prep_kernel<<<B_ROWS / 4, 256, 0, stream>>>(features, labels, F, cls, totals);
  sim_kernel<<<NTILES, 256, 0, stream>>>(F, cls, P_all, P_pos);
  finalize_kernel<<<NT, 256, 0, stream>>>(P_all, P_pos, totals);
  div_kernel<<<1, 1, 0, stream>>>(totals, out);
}

// Round 9
// 92.154 us; speedup vs baseline: 2.3896x; 1.0168x over previous
//
#include <hip/hip_runtime.h>

// StableContrastiveLoss on MI355X (gfx950).  B=4096, D=512, C=10, T=0.07.
// Round 9: sim register-blocking 2x. 128-thread blocks; each wave computes
// 32 rows x 64 cols (acc[2][4]) -> 6 ds_read_b128 per 8 MFMA (was 5 per 4),
// cutting the dominant LDS-read pipe term ~1.67x. Grid stays 2080 (proven
// 8 blk/CU residency). Atomic-free P-store epilogue (R8), XOR-swizzled DMA
// staging (R7, 0 conflicts). NEVER per-block __threadfence (R6).
// ws: F_bf16[4096*512] | cls[4096] | P_all[64*64*64] | P_pos[...] | totals[2]

#define B_ROWS 4096
#define D_DIM  512
#define C_CLS  10
#define NT     64                     // 4096/64 tiles per dim
#define NTILES (NT * (NT + 1) / 2)    // 2080 upper-triangle tiles

typedef __bf16 bf16x8 __attribute__((ext_vector_type(8)));
typedef float  f32x4  __attribute__((ext_vector_type(4)));

// async global->LDS DMA, 16B/lane; LDS dest = wave-uniform base + lane*16
__device__ __forceinline__ void load_lds16(const __bf16* g, __bf16* l) {
  __builtin_amdgcn_global_load_lds(
      (const __attribute__((address_space(1))) unsigned int*)g,
      (__attribute__((address_space(3))) unsigned int*)l, 16, 0, 0);
}

// ---------------- Kernel 1: normalize rows + class extract ----------------
__global__ __launch_bounds__(256) void prep_kernel(
    const float* __restrict__ feats, const float* __restrict__ labels,
    __bf16* __restrict__ F, int* __restrict__ cls,
    float* __restrict__ totals) {
  const int w = threadIdx.x >> 6, lane = threadIdx.x & 63;
  const int row = blockIdx.x * 4 + w;   // one wave per row
  const float* fr = feats + (size_t)row * D_DIM;
  float4 v0 = ((const float4*)fr)[2 * lane];
  float4 v1 = ((const float4*)fr)[2 * lane + 1];
  float ss = v0.x*v0.x + v0.y*v0.y + v0.z*v0.z + v0.w*v0.w
           + v1.x*v1.x + v1.y*v1.y + v1.z*v1.z + v1.w*v1.w;
  #pragma unroll
  for (int m = 1; m < 64; m <<= 1) ss += __shfl_xor(ss, m, 64);
  float inv = 1.0f / sqrtf(ss);

  bf16x8 o;
  o[0] = (__bf16)(v0.x * inv); o[1] = (__bf16)(v0.y * inv);
  o[2] = (__bf16)(v0.z * inv); o[3] = (__bf16)(v0.w * inv);
  o[4] = (__bf16)(v1.x * inv); o[5] = (__bf16)(v1.y * inv);
  o[6] = (__bf16)(v1.z * inv); o[7] = (__bf16)(v1.w * inv);
  *(bf16x8*)(F + (size_t)row * D_DIM + 8 * lane) = o;

  float lv = (lane < C_CLS) ? labels[(size_t)row * C_CLS + lane] : 0.f;
  unsigned long long m = __ballot(lv > 0.5f);
  if (lane == 0) cls[row] = (int)(__ffsll((long long)m) - 1);
  if (blockIdx.x == 0 && threadIdx.x == 0) { totals[0] = 0.f; totals[1] = 0.f; }
}

// --------- Kernel 2: symmetric 64x64-tile sim, 2 waves, no atomics ---------
// Wave w computes rows 32w..32w+31 x all 64 cols. LDS[row][c] = global chunk
// c^(row&7) (DMA-compatible + conflict-free b128). Partials stored exactly
// once: tile(bi,bj) -> P[bi][bj][*] rows, P[bj][bi][*] cols (offdiag).
__global__ __launch_bounds__(128) void sim_kernel(
    const __bf16* __restrict__ F, const int* __restrict__ cls,
    float* __restrict__ P_all, float* __restrict__ P_pos) {
  __shared__ __align__(16) __bf16 Abuf[64 * 64];
  __shared__ __align__(16) __bf16 Bbuf[64 * 64];
  __shared__ int clsA[64], clsB[64];
  __shared__ float g_row_all[64], g_row_pos[64];
  __shared__ float g_col_all[64], g_col_pos[64];

  // triangular tile decode (block-uniform scalar loop, <=64 iters)
  int rem = blockIdx.x, bi = 0, rowlen = NT;
  while (rem >= rowlen) { rem -= rowlen; ++bi; --rowlen; }
  const int bj = bi + rem;
  const int i0 = bi * 64, j0 = bj * 64;
  const bool offdiag = (bi != bj);

  const int t = threadIdx.x;       // 128 threads = 2 waves
  const int w = t >> 6;            // wave 0/1 -> rows 32w..32w+31
  const int lane = t & 63;
  const int q = lane >> 4;         // quad
  const int cl = lane & 15;

  if (t < 64) clsA[t] = cls[i0 + t];
  else        clsB[t - 64] = cls[j0 + t - 64];
  if (t < 64) { g_col_all[t] = 0.f; g_col_pos[t] = 0.f; }

  f32x4 acc[2][4];
  #pragma unroll
  for (int ri = 0; ri < 2; ++ri)
    #pragma unroll
    for (int c = 0; c < 4; ++c) acc[ri][c] = (f32x4){0.f, 0.f, 0.f, 0.f};

  // DMA roles: lane L -> subrow L/8, LDS chunk L%8, global chunk (L%8)^(L/8)
  const int srow = lane >> 3;
  const int sg   = (lane & 7) ^ srow;

  for (int k0 = 0; k0 < D_DIM; k0 += 64) {
    __syncthreads();  // previous readers done (also covers cls/g_col init)
    // wave w stages A rows 32w..32w+31 and B rows 32w..32w+31 (4 DMA each)
    #pragma unroll
    for (int r = 0; r < 4; ++r) {
      const int rowbase = 32 * w + r * 8;   // wave-uniform, multiple of 8
      load_lds16(F + (size_t)(i0 + rowbase + srow) * D_DIM + k0 + sg * 8,
                 &Abuf[rowbase * 64]);
      load_lds16(F + (size_t)(j0 + rowbase + srow) * D_DIM + k0 + sg * 8,
                 &Bbuf[rowbase * 64]);
    }
    __syncthreads();  // barrier drain completes the DMA

    #pragma unroll
    for (int kk = 0; kk < 64; kk += 32) {
      const int g = (kk >> 3) + q;
      const int cc = g ^ (cl & 7);
      bf16x8 af[2], bfr[4];
      #pragma unroll
      for (int ri = 0; ri < 2; ++ri)
        af[ri] = *(const bf16x8*)&Abuf[(32 * w + 16 * ri + cl) * 64 + cc * 8];
      #pragma unroll
      for (int c = 0; c < 4; ++c)
        bfr[c] = *(const bf16x8*)&Bbuf[(16 * c + cl) * 64 + cc * 8];
      #pragma unroll
      for (int ri = 0; ri < 2; ++ri)
        #pragma unroll
        for (int c = 0; c < 4; ++c)
          acc[ri][c] = __builtin_amdgcn_mfma_f32_16x16x32_bf16(
              af[ri], bfr[c], acc[ri][c], 0, 0, 0);
    }
  }

  // Epilogue. D layout (m89/m91): col = lane&15, row = (lane>>4)*4 + reg.
  const float invT = 1.0f / 0.07f;
  float cs_all[4] = {0.f, 0.f, 0.f, 0.f};
  float cs_pos[4] = {0.f, 0.f, 0.f, 0.f};

  #pragma unroll
  for (int ri = 0; ri < 2; ++ri) {
    float sum_all[4] = {0.f, 0.f, 0.f, 0.f};
    float sum_pos[4] = {0.f, 0.f, 0.f, 0.f};
    #pragma unroll
    for (int c = 0; c < 4; ++c) {
      const int jloc = 16*c + cl;
      const int gj = j0 + jloc;
      const int cj = clsB[jloc];
      #pragma unroll
      for (int r = 0; r < 4; ++r) {
        const int iloc = 32*w + 16*ri + q*4 + r;
        const int gi = i0 + iloc;
        float s = acc[ri][c][r] * invT;
        s = fminf(fmaxf(s, -20.f), 20.f);
        const bool diag = (gi == gj);
        float e = diag ? 0.f : __expf(s);
        sum_all[r] += e;
        cs_all[c] += e;
        if (!diag && cj == clsA[iloc]) { sum_pos[r] += e; cs_pos[c] += e; }
      }
    }
    // row sums -> LDS (each row written exactly once: lanes cl==0)
    #pragma unroll
    for (int r = 0; r < 4; ++r) {
      float sa = sum_all[r], sp = sum_pos[r];
      #pragma unroll
      for (int m = 1; m < 16; m <<= 1) {
        sa += __shfl_xor(sa, m, 64);
        sp += __shfl_xor(sp, m, 64);
      }
      if (cl == 0) {
        const int rloc = 32*w + 16*ri + q*4 + r;
        g_row_all[rloc] = sa;
        g_row_pos[rloc] = sp;
      }
    }
  }

  // col sums: reduce across quads, then LDS-scope atomic combine of 2 waves
  if (offdiag) {
    #pragma unroll
    for (int c = 0; c < 4; ++c) {
      float sa = cs_all[c], sp = cs_pos[c];
      sa += __shfl_xor(sa, 16, 64); sa += __shfl_xor(sa, 32, 64);
      sp += __shfl_xor(sp, 16, 64); sp += __shfl_xor(sp, 32, 64);
      if (q == 0) {
        atomicAdd(&g_col_all[16*c + cl], sa);
        atomicAdd(&g_col_pos[16*c + cl], sp);
      }
    }
  }
  __syncthreads();

  // store phase: coalesced 256B stores, exactly-once slot coverage
  if (w == 0) {
    const size_t base_row = ((size_t)bi * 64 + bj) * 64;
    P_all[base_row + lane] = g_row_all[lane];
    P_pos[base_row + lane] = g_row_pos[lane];
  } else if (offdiag) {
    const size_t base_col = ((size_t)bj * 64 + bi) * 64;
    P_all[base_col + lane] = g_col_all[lane];
    P_pos[base_col + lane] = g_col_pos[lane];
  }
}

// ---- Kernel 3: per-strip reduction (64 blocks), tiny atomics to totals ----
__global__ __launch_bounds__(256) void finalize_kernel(
    const float* __restrict__ P_all, const float* __restrict__ P_pos,
    float* __restrict__ totals) {
  __shared__ float Sall[4096], Spos[4096];   // 32 KB
  const int s = blockIdx.x;
  const int t = threadIdx.x;
  for (int i = t; i < 4096; i += 256) {
    Sall[i] = P_all[(size_t)s * 4096 + i];   // coalesced
    Spos[i] = P_pos[(size_t)s * 4096 + i];
  }
  __syncthreads();
  if (t < 64) {   // wave 0: row r = t of this strip
    float a = 0.f, p = 0.f;
    #pragma unroll 8
    for (int k = 0; k < 64; ++k) {   // column sum: 2-way bank alias (free)
      a += Sall[k * 64 + t];
      p += Spos[k * 64 + t];
    }
    float loss = 0.f, cnt = 0.f;
    if (p > 0.f) {                   // valid iff >=1 positive
      loss = -logf(p / (a + 1e-8f) + 1e-8f);
      cnt = 1.f;
    }
    #pragma unroll
    for (int m = 1; m < 64; m <<= 1) {
      loss += __shfl_xor(loss, m, 64);
      cnt  += __shfl_xor(cnt, m, 64);
    }
    if (t == 0) {                    // 128 atomics total across the grid
      atomicAdd(&totals[0], loss);
      atomicAdd(&totals[1], cnt);
    }
  }
}

// ---------------- Kernel 4: scalar division ----------------
__global__ void div_kernel(const float* __restrict__ totals,
                           float* __restrict__ out) {
  out[0] = (totals[1] > 0.f) ? (totals[0] / totals[1]) : 0.f;
}

extern "C" void kernel_launch(void* const* d_in, const int* in_sizes, int n_in,
                              void* d_out, int out_size, void* d_ws, size_t ws_size,
                              hipStream_t stream) {
  const float* features = (const float*)d_in[0];
  const float* labels   = (const float*)d_in[1];
  float* out = (float*)d_out;

  __bf16* F      = (__bf16*)d_ws;
  int*    cls    = (int*)((char*)d_ws + (size_t)B_ROWS * D_DIM * 2);
  float*  P_all  = (float*)((char*)cls + B_ROWS * sizeof(int));
  float*  P_pos  = P_all + (size_t)NT * NT * 64;
  float*  totals = P_pos + (size_t)NT * NT * 64;

  prep_kernel<<<B_ROWS / 4, 256, 0, stream>>>(features, labels, F, cls, totals);
  sim_kernel<<<NTILES, 128, 0, stream>>>(F, cls, P_all, P_pos);
  finalize_kernel<<<NT, 256, 0, stream>>>(P_all, P_pos, totals);
  div_kernel<<<1, 1, 0, stream>>>(totals, out);
}